// Round 5
// baseline (1490.186 us; speedup 1.0000x reference)
//
#include <hip/hip_runtime.h>
#include <hip/hip_bf16.h>
#include <stdint.h>

#define N_NODES 100000
#define N_EDGES 1600000
#define CH 128
#define N_REL 8
#define N_PAD 100096            // N_NODES rounded up to multiple of 128 (GEMM strip pad)
#define SCAN_BLOCKS_D 98        // ceil(N_NODES / 1024)

using frag_ab = __attribute__((ext_vector_type(8))) short;  // 8 bf16
using frag_cd = __attribute__((ext_vector_type(4))) float;  // 4 fp32

__device__ __forceinline__ short f2bs(float f) {
    union { __hip_bfloat16 h; short s; } u;
    u.h = __float2bfloat16(f);
    return u.s;
}

__device__ __forceinline__ uint32_t pack2bf(float a, float b) {
    union { __hip_bfloat16 h; unsigned short s; } ua, ub;
    ua.h = __float2bfloat16(a); ub.h = __float2bfloat16(b);
    return (uint32_t)ua.s | ((uint32_t)ub.s << 16);
}

__device__ __forceinline__ float bf_lo(uint32_t u) { return __uint_as_float(u << 16); }
__device__ __forceinline__ float bf_hi(uint32_t u) { return __uint_as_float(u & 0xffff0000u); }

// ======================= TIER 1: dst-keyed CSR + LDS aggregation =======================

__global__ void count_dst_kernel(const int* __restrict__ ei, int* __restrict__ cnt) {
    int e = blockIdx.x * 256 + threadIdx.x;
    if (e < N_EDGES) atomicAdd(&cnt[ei[N_EDGES + e]], 1);
}

// --- generic two-level scan, 1024 elements per block (256 thr x int4) ---
__global__ void scan1_kernel(const int* __restrict__ cnt, int* __restrict__ bsum, int n) {
    __shared__ int sh[256];
    const int t = threadIdx.x;
    const int base = blockIdx.x * 1024 + t * 4;
    int s = 0;
    if (base + 3 < n) {
        int4 v = *(const int4*)(cnt + base);
        s = v.x + v.y + v.z + v.w;
    } else {
        for (int i = 0; i < 4; ++i) if (base + i < n) s += cnt[base + i];
    }
    sh[t] = s;
    __syncthreads();
    for (int st = 128; st > 0; st >>= 1) {
        if (t < st) sh[t] += sh[t + st];
        __syncthreads();
    }
    if (t == 0) bsum[blockIdx.x] = sh[0];
}

__global__ void scan2_kernel(int* __restrict__ bsum, int nb) {
    __shared__ int sh[1024];
    const int t = threadIdx.x;
    int v = (t < nb) ? bsum[t] : 0;
    sh[t] = v;
    __syncthreads();
    for (int s = 1; s < 1024; s <<= 1) {
        int u = (t >= s) ? sh[t - s] : 0;
        __syncthreads();
        sh[t] += u;
        __syncthreads();
    }
    if (t < nb) bsum[t] = sh[t] - v;   // exclusive
}

// in-place: cnt[i] <- exclusive_prefix_sum(cnt)[i]
__global__ void scan3_kernel(int* __restrict__ cnt, const int* __restrict__ bsum, int n) {
    __shared__ int sh[256];
    const int t = threadIdx.x;
    const int base = blockIdx.x * 1024 + t * 4;
    int4 v = make_int4(0, 0, 0, 0);
    if (base + 3 < n) {
        v = *(const int4*)(cnt + base);
    } else {
        if (base + 0 < n) v.x = cnt[base + 0];
        if (base + 1 < n) v.y = cnt[base + 1];
        if (base + 2 < n) v.z = cnt[base + 2];
        if (base + 3 < n) v.w = cnt[base + 3];
    }
    const int s = v.x + v.y + v.z + v.w;
    sh[t] = s;
    __syncthreads();
    for (int st = 1; st < 256; st <<= 1) {      // Hillis-Steele inclusive
        int u = (t >= st) ? sh[t - st] : 0;
        __syncthreads();
        sh[t] += u;
        __syncthreads();
    }
    int run = bsum[blockIdx.x] + sh[t] - s;     // exclusive prefix for this thread
    const int o0 = run, o1 = o0 + v.x, o2 = o1 + v.y, o3 = o2 + v.z;
    if (base + 3 < n) {
        *(int4*)(cnt + base) = make_int4(o0, o1, o2, o3);
    } else {
        if (base + 0 < n) cnt[base + 0] = o0;
        if (base + 1 < n) cnt[base + 1] = o1;
        if (base + 2 < n) cnt[base + 2] = o2;
        if (base + 3 < n) cnt[base + 3] = o3;
    }
}

// scatter packed (src | r<<17) into dst-sorted slots; offs[] becomes segment ENDS after
__global__ void permute_dst_kernel(const int* __restrict__ ei, const int* __restrict__ et,
                                   int* __restrict__ offs, int* __restrict__ perm) {
    int e = blockIdx.x * 256 + threadIdx.x;
    if (e < N_EDGES) {
        int dst = ei[N_EDGES + e];
        int src = ei[e];
        int r = et[e];
        int pos = atomicAdd(&offs[dst], 1);
        perm[pos] = src | (r << 17);   // N_NODES < 2^17
    }
}

// one block per dst: 4 wave-slots stride the edge list (unroll x4 for MLP),
// accumulate per-relation sums in LDS f32, then write bf16 means.
__global__ __launch_bounds__(256)
void aggregate_lds_kernel(const int* __restrict__ ends, const int* __restrict__ perm,
                          const uint32_t* __restrict__ xb32, uint32_t* __restrict__ sums_u32) {
    __shared__ float acc2[2][N_REL][64];   // [x/y][rel][ch-pair] : bank-conflict-free (2-way)
    __shared__ int cnt8[N_REL];
    const int dst = blockIdx.x;
    const int tid = threadIdx.x;
    const int slot = tid >> 6;
    const int lane = tid & 63;

    {
        float* af = &acc2[0][0][0];
        for (int i = tid; i < 2 * N_REL * 64; i += 256) af[i] = 0.f;
        if (tid < N_REL) cnt8[tid] = 0;
    }
    __syncthreads();

    const int s = (dst == 0) ? 0 : ends[dst - 1];
    const int e = ends[dst];

    for (int k = s + slot; k < e; k += 16) {
        const int k1 = k + 4, k2 = k + 8, k3 = k + 12;
        // 4 broadcast perm loads issued together (clamped), then 4 gathers
        const int p0 = perm[k];
        const int p1 = perm[k1 < e ? k1 : k];
        const int p2 = perm[k2 < e ? k2 : k];
        const int p3 = perm[k3 < e ? k3 : k];
        const uint32_t u0 = xb32[(size_t)(p0 & 0x1FFFF) * 64 + lane];
        const uint32_t u1 = xb32[(size_t)(p1 & 0x1FFFF) * 64 + lane];
        const uint32_t u2 = xb32[(size_t)(p2 & 0x1FFFF) * 64 + lane];
        const uint32_t u3 = xb32[(size_t)(p3 & 0x1FFFF) * 64 + lane];
        {
            const int r = p0 >> 17;
            atomicAdd(&acc2[0][r][lane], bf_lo(u0));
            atomicAdd(&acc2[1][r][lane], bf_hi(u0));
            if (lane == 0) atomicAdd(&cnt8[r], 1);
        }
        if (k1 < e) {
            const int r = p1 >> 17;
            atomicAdd(&acc2[0][r][lane], bf_lo(u1));
            atomicAdd(&acc2[1][r][lane], bf_hi(u1));
            if (lane == 0) atomicAdd(&cnt8[r], 1);
        }
        if (k2 < e) {
            const int r = p2 >> 17;
            atomicAdd(&acc2[0][r][lane], bf_lo(u2));
            atomicAdd(&acc2[1][r][lane], bf_hi(u2));
            if (lane == 0) atomicAdd(&cnt8[r], 1);
        }
        if (k3 < e) {
            const int r = p3 >> 17;
            atomicAdd(&acc2[0][r][lane], bf_lo(u3));
            atomicAdd(&acc2[1][r][lane], bf_hi(u3));
            if (lane == 0) atomicAdd(&cnt8[r], 1);
        }
    }
    __syncthreads();

    // write bf16 means: 512 ch-pair items over 256 threads, coalesced 256B runs
#pragma unroll
    for (int i = tid; i < N_REL * 64; i += 256) {
        const int r = i >> 6, pr = i & 63;
        const int c = cnt8[r];
        const float sc = (c > 1) ? (1.0f / (float)c) : 1.0f;
        sums_u32[((size_t)r * N_PAD + dst) * 64 + pr] =
            pack2bf(acc2[0][r][pr] * sc, acc2[1][r][pr] * sc);
    }
}

// ======================= shared helpers =======================

// x fp32 -> bf16 (flat copy of N*128 elements)
__global__ void xconv_kernel(const float* __restrict__ x, short* __restrict__ xb) {
    int g = blockIdx.x * 256 + threadIdx.x;       // one per 8 elements
    if (g >= N_NODES * CH / 8) return;
    const float4* xp = (const float4*)x;
    float4 a = xp[(size_t)g * 2], b = xp[(size_t)g * 2 + 1];
    frag_ab f;
    f[0] = f2bs(a.x); f[1] = f2bs(a.y); f[2] = f2bs(a.z); f[3] = f2bs(a.w);
    f[4] = f2bs(b.x); f[5] = f2bs(b.y); f[6] = f2bs(b.z); f[7] = f2bs(b.w);
    *(frag_ab*)(xb + (size_t)g * 8) = f;
}

// build swizzled bf16 B: Bsw[chunk][entry][8], entry = ((ks*4+quad)*8+ct)*16+m16
__global__ void bconv_kernel(const float* __restrict__ root, const float* __restrict__ W,
                             short* __restrict__ Bsw) {
    int g = blockIdx.x * 256 + threadIdx.x;
    if (g >= 9 * 2048) return;
    int chunk = g >> 11, entry = g & 2047;
    int m16 = entry & 15, ct = (entry >> 4) & 7, quad = (entry >> 7) & 3, ks = entry >> 9;
    const float* src = (chunk == 0) ? root : W + (size_t)(chunk - 1) * CH * CH;
    int col = ct * 16 + m16, kb = ks * 32 + quad * 8;
    frag_ab f;
#pragma unroll
    for (int j = 0; j < 8; ++j) f[j] = f2bs(src[(size_t)(kb + j) * CH + col]);
    *(frag_ab*)(Bsw + (size_t)g * 8) = f;
}

// out[N,128] = [x | mean_r] @ [root; W_0..W_7] + bias   (K = 1152 = 9 chunks of 128)
__global__ __launch_bounds__(256, 2)
void gemm_fused(const short* __restrict__ xb, const short* __restrict__ sums,
                const short* __restrict__ Bsw, const float* __restrict__ bias,
                float* __restrict__ out) {
    __shared__ short bsh[2048 * 8];   // 32 KB
    const int tid = threadIdx.x;
    const int wave = tid >> 6, lane = tid & 63;
    const int m16 = lane & 15, quad = lane >> 4;
    const int wrow = wave >> 1, wcol = wave & 1;
    const long rowbase = (long)blockIdx.x * 128 + wrow * 64;

    float bcol[4];
#pragma unroll
    for (int ct = 0; ct < 4; ++ct) bcol[ct] = bias[wcol * 64 + ct * 16 + m16];

    frag_cd acc[4][4];
#pragma unroll
    for (int mt = 0; mt < 4; ++mt)
#pragma unroll
        for (int ct = 0; ct < 4; ++ct) acc[mt][ct] = (frag_cd){0.f, 0.f, 0.f, 0.f};

    for (int chunk = 0; chunk < 9; ++chunk) {
        __syncthreads();
        {   // stage 32 KB B chunk
            const float4* src = (const float4*)(Bsw + (size_t)chunk * 2048 * 8);
            float4* dst = (float4*)bsh;
#pragma unroll
            for (int i = 0; i < 8; ++i) dst[tid + 256 * i] = src[tid + 256 * i];
        }
        __syncthreads();
        const short* ab = (chunk == 0) ? xb : sums + (size_t)(chunk - 1) * N_PAD * CH;
#pragma unroll
        for (int ks = 0; ks < 4; ++ks) {
            frag_ab af[4];
#pragma unroll
            for (int mt = 0; mt < 4; ++mt)
                af[mt] = *(const frag_ab*)(ab + (rowbase + mt * 16 + m16) * CH + ks * 32 + quad * 8);
#pragma unroll
            for (int ct = 0; ct < 4; ++ct) {
                frag_ab bf = *(const frag_ab*)(bsh + ((((ks * 4 + quad) * 8) + wcol * 4 + ct) * 16 + m16) * 8);
#pragma unroll
                for (int mt = 0; mt < 4; ++mt)
                    acc[mt][ct] = __builtin_amdgcn_mfma_f32_16x16x32_bf16(af[mt], bf, acc[mt][ct], 0, 0, 0);
            }
        }
    }
#pragma unroll
    for (int mt = 0; mt < 4; ++mt) {
#pragma unroll
        for (int ct = 0; ct < 4; ++ct) {
            const long row0 = rowbase + mt * 16 + quad * 4;
            const int col = wcol * 64 + ct * 16 + m16;
#pragma unroll
            for (int rg = 0; rg < 4; ++rg) {
                long r = row0 + rg;
                if (r < N_NODES) out[r * CH + col] = acc[mt][ct][rg] + bcol[ct];
            }
        }
    }
}

// ======================= fallback tiers (round-1 code) =======================

__global__ void count_rd_kernel(const int* __restrict__ ei, const int* __restrict__ et,
                                int* __restrict__ cnt) {
    int e = blockIdx.x * 256 + threadIdx.x;
    if (e < N_EDGES) {
        int dst = ei[N_EDGES + e];
        int r = et[e];
        atomicAdd(&cnt[r * N_NODES + dst], 1);
    }
}

__global__ void scatter_kernel(const int* __restrict__ ei, const int* __restrict__ et,
                               const float* __restrict__ x, float* __restrict__ sums,
                               int rel) {
    int gid = (blockIdx.x * 256 + threadIdx.x) >> 5;
    int lane = threadIdx.x & 31;
    int ngroups = gridDim.x * 8;
    for (int e = gid; e < N_EDGES; e += ngroups) {
        if (et[e] != rel) continue;
        int src = ei[e];
        int dst = ei[N_EDGES + e];
        float4 v = ((const float4*)(x + (size_t)src * CH))[lane];
        float* s = sums + (size_t)dst * CH + (size_t)lane * 4;
        atomicAdd(s + 0, v.x);
        atomicAdd(s + 1, v.y);
        atomicAdd(s + 2, v.z);
        atomicAdd(s + 3, v.w);
    }
}

__global__ __launch_bounds__(256, 2)
void gemm_kernel(const float* __restrict__ A, const float* __restrict__ B,
                 const float* __restrict__ bias, const int* __restrict__ cnt,
                 float* __restrict__ out, int accumulate) {
    const int wave = threadIdx.x >> 6;
    const int lane = threadIdx.x & 63;
    const int m16 = lane & 15;
    const int quad = lane >> 4;

    frag_ab bfrag[4][8];
#pragma unroll
    for (int ks = 0; ks < 4; ++ks) {
        const int kb = ks * 32 + quad * 8;
#pragma unroll
        for (int ct = 0; ct < 8; ++ct) {
            const int col = ct * 16 + m16;
            frag_ab f;
#pragma unroll
            for (int j = 0; j < 8; ++j)
                f[j] = f2bs(B[(size_t)(kb + j) * CH + col]);
            bfrag[ks][ct] = f;
        }
    }

    const int nstrips = (N_NODES + 63) / 64;
    for (int strip = blockIdx.x; strip < nstrips; strip += gridDim.x) {
        const int row = strip * 64 + wave * 16 + m16;
        const bool valid = row < N_NODES;
        float scale = 1.0f;
        if (cnt != nullptr && valid) {
            int c = cnt[row];
            if (c > 1) scale = 1.0f / (float)c;
        }
        const float4* arow = (const float4*)(A + (size_t)(valid ? row : 0) * CH);
        frag_cd acc[8];
#pragma unroll
        for (int ct = 0; ct < 8; ++ct) acc[ct] = (frag_cd){0.f, 0.f, 0.f, 0.f};
#pragma unroll
        for (int ks = 0; ks < 4; ++ks) {
            float4 a0 = arow[ks * 8 + quad * 2];
            float4 a1 = arow[ks * 8 + quad * 2 + 1];
            frag_ab af;
            af[0] = f2bs(a0.x * scale); af[1] = f2bs(a0.y * scale);
            af[2] = f2bs(a0.z * scale); af[3] = f2bs(a0.w * scale);
            af[4] = f2bs(a1.x * scale); af[5] = f2bs(a1.y * scale);
            af[6] = f2bs(a1.z * scale); af[7] = f2bs(a1.w * scale);
#pragma unroll
            for (int ct = 0; ct < 8; ++ct)
                acc[ct] = __builtin_amdgcn_mfma_f32_16x16x32_bf16(af, bfrag[ks][ct], acc[ct], 0, 0, 0);
        }
        const int obase = strip * 64 + wave * 16 + quad * 4;
#pragma unroll
        for (int ct = 0; ct < 8; ++ct) {
            const int col = ct * 16 + m16;
#pragma unroll
            for (int rg = 0; rg < 4; ++rg) {
                const int r = obase + rg;
                if (r < N_NODES) {
                    const size_t idx = (size_t)r * CH + col;
                    if (accumulate) out[idx] += acc[ct][rg];
                    else out[idx] = acc[ct][rg] + bias[col];
                }
            }
        }
    }
}

__global__ void edge_transform_kernel(const int* __restrict__ ei, const int* __restrict__ et,
                                      const float* __restrict__ x, const float* __restrict__ W,
                                      const int* __restrict__ cnt, float* __restrict__ out) {
    __shared__ float xs[CH];
    const int tid = threadIdx.x;
    for (int e = blockIdx.x; e < N_EDGES; e += gridDim.x) {
        const int src = ei[e];
        const int dst = ei[N_EDGES + e];
        const int r = et[e];
        __syncthreads();
        xs[tid] = x[(size_t)src * CH + tid];
        __syncthreads();
        const int c = cnt[r * N_NODES + dst];
        const float scale = (c > 1) ? (1.0f / (float)c) : 1.0f;
        const float* Wr = W + (size_t)r * CH * CH;
        float acc = 0.f;
#pragma unroll 8
        for (int k = 0; k < CH; ++k) acc += xs[k] * Wr[(size_t)k * CH + tid];
        atomicAdd(&out[(size_t)dst * CH + tid], acc * scale);
    }
}

// ======================= launch =======================

static inline size_t al512(size_t x) { return (x + 511) & ~(size_t)511; }

extern "C" void kernel_launch(void* const* d_in, const int* in_sizes, int n_in,
                              void* d_out, int out_size, void* d_ws, size_t ws_size,
                              hipStream_t stream) {
    const float* x    = (const float*)d_in[0];
    const int*   ei   = (const int*)d_in[1];   // [2, E]: row0=src, row1=dst
    const int*   et   = (const int*)d_in[2];   // [E]
    const float* W    = (const float*)d_in[3]; // [R,128,128]
    const float* root = (const float*)d_in[4]; // [128,128]
    const float* bias = (const float*)d_in[5]; // [128]
    float* out = (float*)d_out;

    // ---- tier-1 workspace layout (dst-keyed CSR) ----
    size_t o = 0;
    const size_t o_cnt  = o; o += al512((size_t)N_NODES * 4);        // offs/ends in place
    const size_t o_bsum = o; o += al512((size_t)SCAN_BLOCKS_D * 4);
    const size_t o_perm = o; o += al512((size_t)N_EDGES * 4);
    const size_t o_bsw  = o; o += al512((size_t)9 * 2048 * 16);
    const size_t o_xb   = o; o += al512((size_t)N_PAD * CH * 2);
    const size_t o_sums = o; o += al512((size_t)N_REL * N_PAD * CH * 2);
    const size_t need_t1 = o;

    const size_t cnt_bytes = (size_t)N_REL * N_NODES * sizeof(int);
    const size_t cnt_rsv   = al512(cnt_bytes);
    const size_t sums51    = (size_t)N_NODES * CH * sizeof(float);

    char* ws = (char*)d_ws;
    if (ws_size >= need_t1) {
        int*   cnt  = (int*)(ws + o_cnt);
        int*   bsum = (int*)(ws + o_bsum);
        int*   perm = (int*)(ws + o_perm);
        short* Bsw  = (short*)(ws + o_bsw);
        short* xb   = (short*)(ws + o_xb);
        short* sums = (short*)(ws + o_sums);

        hipMemsetAsync(cnt, 0, (size_t)N_NODES * 4, stream);
        count_dst_kernel<<<(N_EDGES + 255) / 256, 256, 0, stream>>>(ei, cnt);
        scan1_kernel<<<SCAN_BLOCKS_D, 256, 0, stream>>>(cnt, bsum, N_NODES);
        scan2_kernel<<<1, 1024, 0, stream>>>(bsum, SCAN_BLOCKS_D);
        scan3_kernel<<<SCAN_BLOCKS_D, 256, 0, stream>>>(cnt, bsum, N_NODES);
        permute_dst_kernel<<<(N_EDGES + 255) / 256, 256, 0, stream>>>(ei, et, cnt, perm);
        xconv_kernel<<<(N_NODES * CH / 8 + 255) / 256, 256, 0, stream>>>(x, xb);
        bconv_kernel<<<(9 * 2048 + 255) / 256, 256, 0, stream>>>(root, W, Bsw);
        aggregate_lds_kernel<<<N_NODES, 256, 0, stream>>>(
            cnt, perm, (const uint32_t*)xb, (uint32_t*)sums);
        gemm_fused<<<N_PAD / 128, 256, 0, stream>>>(xb, sums, Bsw, bias, out);
    } else if (ws_size >= cnt_rsv + sums51) {
        int*   cnt  = (int*)d_ws;
        float* sums = (float*)((char*)d_ws + cnt_rsv);
        hipMemsetAsync(cnt, 0, cnt_bytes, stream);
        count_rd_kernel<<<(N_EDGES + 255) / 256, 256, 0, stream>>>(ei, et, cnt);
        gemm_kernel<<<512, 256, 0, stream>>>(x, root, bias, nullptr, out, 0);
        for (int r = 0; r < N_REL; ++r) {
            hipMemsetAsync(sums, 0, sums51, stream);
            scatter_kernel<<<6400, 256, 0, stream>>>(ei, et, x, sums, r);
            gemm_kernel<<<512, 256, 0, stream>>>(sums, W + (size_t)r * CH * CH,
                                                 nullptr, cnt + (size_t)r * N_NODES, out, 1);
        }
    } else {
        int* cnt = (int*)d_ws;
        hipMemsetAsync(cnt, 0, cnt_bytes, stream);
        count_rd_kernel<<<(N_EDGES + 255) / 256, 256, 0, stream>>>(ei, et, cnt);
        gemm_kernel<<<512, 256, 0, stream>>>(x, root, bias, nullptr, out, 0);
        edge_transform_kernel<<<65536, CH, 0, stream>>>(ei, et, x, W, cnt, out);
    }
}

// Round 6
// 549.218 us; speedup vs baseline: 2.7133x; 2.7133x over previous
//
#include <hip/hip_runtime.h>
#include <hip/hip_bf16.h>
#include <stdint.h>

#define N_NODES 100000
#define N_EDGES 1600000
#define CH 128
#define N_REL 8
#define N_PAD 100096            // N_NODES rounded up to multiple of 128 (GEMM strip pad)
#define N_KEYS (N_NODES * N_REL)

#define SCAN_BLOCKS_K 782       // ceil(N_KEYS / 1024)
#define SCAN_BLOCKS_D 98        // ceil(N_NODES / 1024)

using frag_ab = __attribute__((ext_vector_type(8))) short;  // 8 bf16
using frag_cd = __attribute__((ext_vector_type(4))) float;  // 4 fp32

__device__ __forceinline__ short f2bs(float f) {
    union { __hip_bfloat16 h; short s; } u;
    u.h = __float2bfloat16(f);
    return u.s;
}

__device__ __forceinline__ uint32_t pack2bf(float a, float b) {
    union { __hip_bfloat16 h; unsigned short s; } ua, ub;
    ua.h = __float2bfloat16(a); ub.h = __float2bfloat16(b);
    return (uint32_t)ua.s | ((uint32_t)ub.s << 16);
}

__device__ __forceinline__ float bf_lo(uint32_t u) { return __uint_as_float(u << 16); }
__device__ __forceinline__ float bf_hi(uint32_t u) { return __uint_as_float(u & 0xffff0000u); }

// ======================= TIER 1: CSR keyed by (dst*8 + rel) =======================

__global__ void count_key_kernel(const int* __restrict__ ei, const int* __restrict__ et,
                                 int* __restrict__ cnt) {
    int e = blockIdx.x * 256 + threadIdx.x;
    if (e < N_EDGES) {
        int dst = ei[N_EDGES + e];
        int r = et[e];
        atomicAdd(&cnt[dst * N_REL + r], 1);
    }
}

// --- generic two-level scan, 1024 elements per block (256 thr x int4) ---
__global__ void scan1_kernel(const int* __restrict__ cnt, int* __restrict__ bsum, int n) {
    __shared__ int sh[256];
    const int t = threadIdx.x;
    const int base = blockIdx.x * 1024 + t * 4;
    int s = 0;
    if (base + 3 < n) {
        int4 v = *(const int4*)(cnt + base);
        s = v.x + v.y + v.z + v.w;
    } else {
        for (int i = 0; i < 4; ++i) if (base + i < n) s += cnt[base + i];
    }
    sh[t] = s;
    __syncthreads();
    for (int st = 128; st > 0; st >>= 1) {
        if (t < st) sh[t] += sh[t + st];
        __syncthreads();
    }
    if (t == 0) bsum[blockIdx.x] = sh[0];
}

__global__ void scan2_kernel(int* __restrict__ bsum, int nb) {
    __shared__ int sh[1024];
    const int t = threadIdx.x;
    int v = (t < nb) ? bsum[t] : 0;
    sh[t] = v;
    __syncthreads();
    for (int s = 1; s < 1024; s <<= 1) {
        int u = (t >= s) ? sh[t - s] : 0;
        __syncthreads();
        sh[t] += u;
        __syncthreads();
    }
    if (t < nb) bsum[t] = sh[t] - v;   // exclusive
}

// in-place: cnt[i] <- exclusive_prefix_sum(cnt)[i]
__global__ void scan3_kernel(int* __restrict__ cnt, const int* __restrict__ bsum, int n) {
    __shared__ int sh[256];
    const int t = threadIdx.x;
    const int base = blockIdx.x * 1024 + t * 4;
    int4 v = make_int4(0, 0, 0, 0);
    if (base + 3 < n) {
        v = *(const int4*)(cnt + base);
    } else {
        if (base + 0 < n) v.x = cnt[base + 0];
        if (base + 1 < n) v.y = cnt[base + 1];
        if (base + 2 < n) v.z = cnt[base + 2];
        if (base + 3 < n) v.w = cnt[base + 3];
    }
    const int s = v.x + v.y + v.z + v.w;
    sh[t] = s;
    __syncthreads();
    for (int st = 1; st < 256; st <<= 1) {      // Hillis-Steele inclusive
        int u = (t >= st) ? sh[t - st] : 0;
        __syncthreads();
        sh[t] += u;
        __syncthreads();
    }
    int run = bsum[blockIdx.x] + sh[t] - s;     // exclusive prefix for this thread
    const int o0 = run, o1 = o0 + v.x, o2 = o1 + v.y, o3 = o2 + v.z;
    if (base + 3 < n) {
        *(int4*)(cnt + base) = make_int4(o0, o1, o2, o3);
    } else {
        if (base + 0 < n) cnt[base + 0] = o0;
        if (base + 1 < n) cnt[base + 1] = o1;
        if (base + 2 < n) cnt[base + 2] = o2;
        if (base + 3 < n) cnt[base + 3] = o3;
    }
}

// scatter src into (dst,rel)-sorted slots; offs[] doubles as cursor and ends as segment-END
__global__ void permute_key_kernel(const int* __restrict__ ei, const int* __restrict__ et,
                                   int* __restrict__ offs, int* __restrict__ perm) {
    int e = blockIdx.x * 256 + threadIdx.x;
    if (e < N_EDGES) {
        int dst = ei[N_EDGES + e];
        int src = ei[e];
        int r = et[e];
        int pos = atomicAdd(&offs[dst * N_REL + r], 1);
        perm[pos] = src;
    }
}

// one wave per (dst, rel-pair): both relation segments are adjacent in perm,
// so run ONE flat loop over [s0,e1) with clamped unroll-4 (4 gathers in flight),
// attributing each edge to rel r0 or r0+1 via the wave-uniform predicate k<e0.
__global__ __launch_bounds__(256)
void aggregate2_kernel(const int* __restrict__ ends, const int* __restrict__ perm,
                       const uint32_t* __restrict__ xb32, uint32_t* __restrict__ sums_u32) {
    const int wid = (blockIdx.x * 256 + threadIdx.x) >> 6;    // [0, N_NODES*4)
    const int lane = threadIdx.x & 63;
    const int dst = wid >> 2;
    if (dst >= N_NODES) return;
    const int r0 = (wid & 3) * 2;
    const int key0 = dst * N_REL + r0;

    const int s0 = (key0 == 0) ? 0 : ends[key0 - 1];
    const int e0 = ends[key0];
    const int e1 = ends[key0 + 1];

    // two accumulator banks per relation for ILP
    float x0a = 0.f, y0a = 0.f, x1a = 0.f, y1a = 0.f;
    float x0b = 0.f, y0b = 0.f, x1b = 0.f, y1b = 0.f;

    for (int k = s0; k < e1; k += 4) {
        const int kb = k + 1, kc = k + 2, kd = k + 3;
        // 4 broadcast perm loads (clamped), then 4 independent gathers
        const int pa = perm[k];
        const int pb = perm[kb < e1 ? kb : k];
        const int pc = perm[kc < e1 ? kc : k];
        const int pd = perm[kd < e1 ? kd : k];
        const uint32_t ua = xb32[(size_t)pa * 64 + lane];
        const uint32_t ub = xb32[(size_t)pb * 64 + lane];
        const uint32_t uc = xb32[(size_t)pc * 64 + lane];
        const uint32_t ud = xb32[(size_t)pd * 64 + lane];
        {   // k always valid; k<e0 is wave-uniform
            const float lo = bf_lo(ua), hi = bf_hi(ua);
            if (k < e0) { x0a += lo; y0a += hi; } else { x1a += lo; y1a += hi; }
        }
        if (kb < e1) {
            const float lo = bf_lo(ub), hi = bf_hi(ub);
            if (kb < e0) { x0b += lo; y0b += hi; } else { x1b += lo; y1b += hi; }
        }
        if (kc < e1) {
            const float lo = bf_lo(uc), hi = bf_hi(uc);
            if (kc < e0) { x0a += lo; y0a += hi; } else { x1a += lo; y1a += hi; }
        }
        if (kd < e1) {
            const float lo = bf_lo(ud), hi = bf_hi(ud);
            if (kd < e0) { x0b += lo; y0b += hi; } else { x1b += lo; y1b += hi; }
        }
    }

    const int c0 = e0 - s0, c1 = e1 - e0;
    const float sc0 = (c0 > 1) ? (1.0f / (float)c0) : 1.0f;
    const float sc1 = (c1 > 1) ? (1.0f / (float)c1) : 1.0f;
    sums_u32[((size_t)r0 * N_PAD + dst) * 64 + lane] =
        pack2bf((x0a + x0b) * sc0, (y0a + y0b) * sc0);
    sums_u32[((size_t)(r0 + 1) * N_PAD + dst) * 64 + lane] =
        pack2bf((x1a + x1b) * sc1, (y1a + y1b) * sc1);
}

// ======================= shared helpers =======================

// x fp32 -> bf16 (flat copy of N*128 elements)
__global__ void xconv_kernel(const float* __restrict__ x, short* __restrict__ xb) {
    int g = blockIdx.x * 256 + threadIdx.x;       // one per 8 elements
    if (g >= N_NODES * CH / 8) return;
    const float4* xp = (const float4*)x;
    float4 a = xp[(size_t)g * 2], b = xp[(size_t)g * 2 + 1];
    frag_ab f;
    f[0] = f2bs(a.x); f[1] = f2bs(a.y); f[2] = f2bs(a.z); f[3] = f2bs(a.w);
    f[4] = f2bs(b.x); f[5] = f2bs(b.y); f[6] = f2bs(b.z); f[7] = f2bs(b.w);
    *(frag_ab*)(xb + (size_t)g * 8) = f;
}

// build swizzled bf16 B: Bsw[chunk][entry][8], entry = ((ks*4+quad)*8+ct)*16+m16
__global__ void bconv_kernel(const float* __restrict__ root, const float* __restrict__ W,
                             short* __restrict__ Bsw) {
    int g = blockIdx.x * 256 + threadIdx.x;
    if (g >= 9 * 2048) return;
    int chunk = g >> 11, entry = g & 2047;
    int m16 = entry & 15, ct = (entry >> 4) & 7, quad = (entry >> 7) & 3, ks = entry >> 9;
    const float* src = (chunk == 0) ? root : W + (size_t)(chunk - 1) * CH * CH;
    int col = ct * 16 + m16, kb = ks * 32 + quad * 8;
    frag_ab f;
#pragma unroll
    for (int j = 0; j < 8; ++j) f[j] = f2bs(src[(size_t)(kb + j) * CH + col]);
    *(frag_ab*)(Bsw + (size_t)g * 8) = f;
}

// out[N,128] = [x | mean_r] @ [root; W_0..W_7] + bias   (K = 1152 = 9 chunks of 128)
__global__ __launch_bounds__(256, 2)
void gemm_fused(const short* __restrict__ xb, const short* __restrict__ sums,
                const short* __restrict__ Bsw, const float* __restrict__ bias,
                float* __restrict__ out) {
    __shared__ short bsh[2048 * 8];   // 32 KB
    const int tid = threadIdx.x;
    const int wave = tid >> 6, lane = tid & 63;
    const int m16 = lane & 15, quad = lane >> 4;
    const int wrow = wave >> 1, wcol = wave & 1;
    const long rowbase = (long)blockIdx.x * 128 + wrow * 64;

    float bcol[4];
#pragma unroll
    for (int ct = 0; ct < 4; ++ct) bcol[ct] = bias[wcol * 64 + ct * 16 + m16];

    frag_cd acc[4][4];
#pragma unroll
    for (int mt = 0; mt < 4; ++mt)
#pragma unroll
        for (int ct = 0; ct < 4; ++ct) acc[mt][ct] = (frag_cd){0.f, 0.f, 0.f, 0.f};

    for (int chunk = 0; chunk < 9; ++chunk) {
        __syncthreads();
        {   // stage 32 KB B chunk
            const float4* src = (const float4*)(Bsw + (size_t)chunk * 2048 * 8);
            float4* dst = (float4*)bsh;
#pragma unroll
            for (int i = 0; i < 8; ++i) dst[tid + 256 * i] = src[tid + 256 * i];
        }
        __syncthreads();
        const short* ab = (chunk == 0) ? xb : sums + (size_t)(chunk - 1) * N_PAD * CH;
#pragma unroll
        for (int ks = 0; ks < 4; ++ks) {
            frag_ab af[4];
#pragma unroll
            for (int mt = 0; mt < 4; ++mt)
                af[mt] = *(const frag_ab*)(ab + (rowbase + mt * 16 + m16) * CH + ks * 32 + quad * 8);
#pragma unroll
            for (int ct = 0; ct < 4; ++ct) {
                frag_ab bf = *(const frag_ab*)(bsh + ((((ks * 4 + quad) * 8) + wcol * 4 + ct) * 16 + m16) * 8);
#pragma unroll
                for (int mt = 0; mt < 4; ++mt)
                    acc[mt][ct] = __builtin_amdgcn_mfma_f32_16x16x32_bf16(af[mt], bf, acc[mt][ct], 0, 0, 0);
            }
        }
    }
#pragma unroll
    for (int mt = 0; mt < 4; ++mt) {
#pragma unroll
        for (int ct = 0; ct < 4; ++ct) {
            const long row0 = rowbase + mt * 16 + quad * 4;
            const int col = wcol * 64 + ct * 16 + m16;
#pragma unroll
            for (int rg = 0; rg < 4; ++rg) {
                long r = row0 + rg;
                if (r < N_NODES) out[r * CH + col] = acc[mt][ct][rg] + bcol[ct];
            }
        }
    }
}

// ======================= fallback tiers (round-1 code) =======================

__global__ void count_rd_kernel(const int* __restrict__ ei, const int* __restrict__ et,
                                int* __restrict__ cnt) {
    int e = blockIdx.x * 256 + threadIdx.x;
    if (e < N_EDGES) {
        int dst = ei[N_EDGES + e];
        int r = et[e];
        atomicAdd(&cnt[r * N_NODES + dst], 1);
    }
}

__global__ void scatter_kernel(const int* __restrict__ ei, const int* __restrict__ et,
                               const float* __restrict__ x, float* __restrict__ sums,
                               int rel) {
    int gid = (blockIdx.x * 256 + threadIdx.x) >> 5;
    int lane = threadIdx.x & 31;
    int ngroups = gridDim.x * 8;
    for (int e = gid; e < N_EDGES; e += ngroups) {
        if (et[e] != rel) continue;
        int src = ei[e];
        int dst = ei[N_EDGES + e];
        float4 v = ((const float4*)(x + (size_t)src * CH))[lane];
        float* s = sums + (size_t)dst * CH + (size_t)lane * 4;
        atomicAdd(s + 0, v.x);
        atomicAdd(s + 1, v.y);
        atomicAdd(s + 2, v.z);
        atomicAdd(s + 3, v.w);
    }
}

__global__ __launch_bounds__(256, 2)
void gemm_kernel(const float* __restrict__ A, const float* __restrict__ B,
                 const float* __restrict__ bias, const int* __restrict__ cnt,
                 float* __restrict__ out, int accumulate) {
    const int wave = threadIdx.x >> 6;
    const int lane = threadIdx.x & 63;
    const int m16 = lane & 15;
    const int quad = lane >> 4;

    frag_ab bfrag[4][8];
#pragma unroll
    for (int ks = 0; ks < 4; ++ks) {
        const int kb = ks * 32 + quad * 8;
#pragma unroll
        for (int ct = 0; ct < 8; ++ct) {
            const int col = ct * 16 + m16;
            frag_ab f;
#pragma unroll
            for (int j = 0; j < 8; ++j)
                f[j] = f2bs(B[(size_t)(kb + j) * CH + col]);
            bfrag[ks][ct] = f;
        }
    }

    const int nstrips = (N_NODES + 63) / 64;
    for (int strip = blockIdx.x; strip < nstrips; strip += gridDim.x) {
        const int row = strip * 64 + wave * 16 + m16;
        const bool valid = row < N_NODES;
        float scale = 1.0f;
        if (cnt != nullptr && valid) {
            int c = cnt[row];
            if (c > 1) scale = 1.0f / (float)c;
        }
        const float4* arow = (const float4*)(A + (size_t)(valid ? row : 0) * CH);
        frag_cd acc[8];
#pragma unroll
        for (int ct = 0; ct < 8; ++ct) acc[ct] = (frag_cd){0.f, 0.f, 0.f, 0.f};
#pragma unroll
        for (int ks = 0; ks < 4; ++ks) {
            float4 a0 = arow[ks * 8 + quad * 2];
            float4 a1 = arow[ks * 8 + quad * 2 + 1];
            frag_ab af;
            af[0] = f2bs(a0.x * scale); af[1] = f2bs(a0.y * scale);
            af[2] = f2bs(a0.z * scale); af[3] = f2bs(a0.w * scale);
            af[4] = f2bs(a1.x * scale); af[5] = f2bs(a1.y * scale);
            af[6] = f2bs(a1.z * scale); af[7] = f2bs(a1.w * scale);
#pragma unroll
            for (int ct = 0; ct < 8; ++ct)
                acc[ct] = __builtin_amdgcn_mfma_f32_16x16x32_bf16(af, bfrag[ks][ct], acc[ct], 0, 0, 0);
        }
        const int obase = strip * 64 + wave * 16 + quad * 4;
#pragma unroll
        for (int ct = 0; ct < 8; ++ct) {
            const int col = ct * 16 + m16;
#pragma unroll
            for (int rg = 0; rg < 4; ++rg) {
                const int r = obase + rg;
                if (r < N_NODES) {
                    const size_t idx = (size_t)r * CH + col;
                    if (accumulate) out[idx] += acc[ct][rg];
                    else out[idx] = acc[ct][rg] + bias[col];
                }
            }
        }
    }
}

__global__ void edge_transform_kernel(const int* __restrict__ ei, const int* __restrict__ et,
                                      const float* __restrict__ x, const float* __restrict__ W,
                                      const int* __restrict__ cnt, float* __restrict__ out) {
    __shared__ float xs[CH];
    const int tid = threadIdx.x;
    for (int e = blockIdx.x; e < N_EDGES; e += gridDim.x) {
        const int src = ei[e];
        const int dst = ei[N_EDGES + e];
        const int r = et[e];
        __syncthreads();
        xs[tid] = x[(size_t)src * CH + tid];
        __syncthreads();
        const int c = cnt[r * N_NODES + dst];
        const float scale = (c > 1) ? (1.0f / (float)c) : 1.0f;
        const float* Wr = W + (size_t)r * CH * CH;
        float acc = 0.f;
#pragma unroll 8
        for (int k = 0; k < CH; ++k) acc += xs[k] * Wr[(size_t)k * CH + tid];
        atomicAdd(&out[(size_t)dst * CH + tid], acc * scale);
    }
}

// ======================= launch =======================

static inline size_t al512(size_t x) { return (x + 511) & ~(size_t)511; }

extern "C" void kernel_launch(void* const* d_in, const int* in_sizes, int n_in,
                              void* d_out, int out_size, void* d_ws, size_t ws_size,
                              hipStream_t stream) {
    const float* x    = (const float*)d_in[0];
    const int*   ei   = (const int*)d_in[1];   // [2, E]: row0=src, row1=dst
    const int*   et   = (const int*)d_in[2];   // [E]
    const float* W    = (const float*)d_in[3]; // [R,128,128]
    const float* root = (const float*)d_in[4]; // [128,128]
    const float* bias = (const float*)d_in[5]; // [128]
    float* out = (float*)d_out;

    // ---- tier-1 workspace layout (key = dst*8+rel) ----
    size_t o = 0;
    const size_t o_cnt  = o; o += al512((size_t)N_KEYS * 4);         // offs/ends in place
    const size_t o_bsum = o; o += al512((size_t)SCAN_BLOCKS_K * 4);
    const size_t o_perm = o; o += al512((size_t)N_EDGES * 4);
    const size_t o_bsw  = o; o += al512((size_t)9 * 2048 * 16);
    const size_t o_xb   = o; o += al512((size_t)N_PAD * CH * 2);
    const size_t o_sums = o; o += al512((size_t)N_REL * N_PAD * CH * 2);
    const size_t need_t1 = o;

    const size_t cnt_bytes = (size_t)N_REL * N_NODES * sizeof(int);
    const size_t cnt_rsv   = al512(cnt_bytes);
    const size_t sums51    = (size_t)N_NODES * CH * sizeof(float);

    char* ws = (char*)d_ws;
    if (ws_size >= need_t1) {
        int*   cnt  = (int*)(ws + o_cnt);
        int*   bsum = (int*)(ws + o_bsum);
        int*   perm = (int*)(ws + o_perm);
        short* Bsw  = (short*)(ws + o_bsw);
        short* xb   = (short*)(ws + o_xb);
        short* sums = (short*)(ws + o_sums);

        hipMemsetAsync(cnt, 0, (size_t)N_KEYS * 4, stream);
        count_key_kernel<<<(N_EDGES + 255) / 256, 256, 0, stream>>>(ei, et, cnt);
        scan1_kernel<<<SCAN_BLOCKS_K, 256, 0, stream>>>(cnt, bsum, N_KEYS);
        scan2_kernel<<<1, 1024, 0, stream>>>(bsum, SCAN_BLOCKS_K);
        scan3_kernel<<<SCAN_BLOCKS_K, 256, 0, stream>>>(cnt, bsum, N_KEYS);
        permute_key_kernel<<<(N_EDGES + 255) / 256, 256, 0, stream>>>(ei, et, cnt, perm);
        xconv_kernel<<<(N_NODES * CH / 8 + 255) / 256, 256, 0, stream>>>(x, xb);
        bconv_kernel<<<(9 * 2048 + 255) / 256, 256, 0, stream>>>(root, W, Bsw);
        aggregate2_kernel<<<(N_NODES * 4 * 64) / 256, 256, 0, stream>>>(
            cnt, perm, (const uint32_t*)xb, (uint32_t*)sums);
        gemm_fused<<<N_PAD / 128, 256, 0, stream>>>(xb, sums, Bsw, bias, out);
    } else if (ws_size >= cnt_rsv + sums51) {
        int*   cnt  = (int*)d_ws;
        float* sums = (float*)((char*)d_ws + cnt_rsv);
        hipMemsetAsync(cnt, 0, cnt_bytes, stream);
        count_rd_kernel<<<(N_EDGES + 255) / 256, 256, 0, stream>>>(ei, et, cnt);
        gemm_kernel<<<512, 256, 0, stream>>>(x, root, bias, nullptr, out, 0);
        for (int r = 0; r < N_REL; ++r) {
            hipMemsetAsync(sums, 0, sums51, stream);
            scatter_kernel<<<6400, 256, 0, stream>>>(ei, et, x, sums, r);
            gemm_kernel<<<512, 256, 0, stream>>>(sums, W + (size_t)r * CH * CH,
                                                 nullptr, cnt + (size_t)r * N_NODES, out, 1);
        }
    } else {
        int* cnt = (int*)d_ws;
        hipMemsetAsync(cnt, 0, cnt_bytes, stream);
        count_rd_kernel<<<(N_EDGES + 255) / 256, 256, 0, stream>>>(ei, et, cnt);
        gemm_kernel<<<512, 256, 0, stream>>>(x, root, bias, nullptr, out, 0);
        edge_transform_kernel<<<65536, CH, 0, stream>>>(ei, et, x, W, cnt, out);
    }
}